// Round 6
// baseline (236.901 us; speedup 1.0000x reference)
//
#include <hip/hip_runtime.h>
#include <math.h>
#include <stdint.h>

// ContentAttention fused, round 6.
// R5 post-mortem: attn_v5 (named-dbuf, fragment-order loads) dropped to ~50us,
// but convert_frag regressed to 83us at 2.4 TB/s (30% peak): lane l read
// M[g16*16+(l&15)][(l>>4)*8] -> 16 lanes hit 16 rows 4KB apart, 32B each
// (64 isolated transactions/wave). R6 permutes the slot->thread assignment
// (l = ((t&3)<<4)|((t>>2)&15)) so quads of lanes read 128B contiguous runs of
// one row (16x128B segments/wave) while writes still densely cover the same
// 1KB fragment blocks (permuted within = still full cache lines).
// attn_v5 unchanged. Fallbacks v5k / v1 retained.

#define NB 32
#define NQ 512
#define NK 512
#define ND 1024
#define BK 32
#define NT (ND / BK)            // 32 k-tiles
#define BM1 64                  // fallback rows/block
#define TILE_BYTES 65536        // per (batch,kt): 32 groups x (1KB hi + 1KB lo)
#define WS_K ((size_t)NB * NT * TILE_BYTES)       // 64 MiB K fragment image
#define MASK_BYTES ((size_t)NB * NK * 4)          // 64 KiB
#define WS_Q_OFF (WS_K + MASK_BYTES)
#define WS_V5 (WS_Q_OFF + WS_K)                   // + 64 MiB Q fragment image
#define WS_V5K (WS_K + MASK_BYTES)

typedef __attribute__((ext_vector_type(8))) short short8;
typedef __attribute__((ext_vector_type(4))) float f32x4;

__device__ __forceinline__ void bf_split(float x, unsigned& hbits, float& lo) {
  unsigned u = __float_as_uint(x);
  unsigned r = u + 0x7fffu + ((u >> 16) & 1u);
  hbits = r & 0xffff0000u;
  lo = x - __uint_as_float(hbits);
}
__device__ __forceinline__ unsigned pack_rn(float x0, float x1) {
  unsigned u0 = __float_as_uint(x0), u1 = __float_as_uint(x1);
  unsigned r0 = u0 + 0x7fffu + ((u0 >> 16) & 1u);
  unsigned r1 = u1 + 0x7fffu + ((u1 >> 16) & 1u);
  return (r0 >> 16) | (r1 & 0xffff0000u);
}

// 8 fp32 -> bf16-hi frag + bf16-lo frag (each 8 bf16 = 16 B).
__device__ __forceinline__ void cvt8(const float4& v0, const float4& v1,
                                     short8& hi8, short8& lo8) {
  float f[8] = {v0.x, v0.y, v0.z, v0.w, v1.x, v1.y, v1.z, v1.w};
  unsigned hh[8];
  float ll[8];
#pragma unroll
  for (int i = 0; i < 8; ++i) bf_split(f[i], hh[i], ll[i]);
  union { uint4 u; short8 s; } H, L;
  H.u = make_uint4((hh[0] >> 16) | (hh[1] & 0xffff0000u),
                   (hh[2] >> 16) | (hh[3] & 0xffff0000u),
                   (hh[4] >> 16) | (hh[5] & 0xffff0000u),
                   (hh[6] >> 16) | (hh[7] & 0xffff0000u));
  L.u = make_uint4(pack_rn(ll[0], ll[1]), pack_rn(ll[2], ll[3]),
                   pack_rn(ll[4], ll[5]), pack_rn(ll[6], ll[7]));
  hi8 = H.s;
  lo8 = L.s;
}

// ---------------------------------------------------------------------------
// convert_frag: matrix fp32 -> MFMA fragment order (layout HW-verified R4/R5).
// Fragment slot (g16, l) holds M[row = g16*16 + (l&15)][kt*32 + (l>>4)*8 + j].
// R6: thread t6 (within its 64-lane wave) services slot
//   l = ((t6&3)<<4) | ((t6>>2)&15)
// so reads are 128-B row-runs (coalesced) and writes still densely cover the
// wave's 1KB hi / 1KB lo fragment blocks.
// Grid 2*nkq: blocks [0,nkq) convert K (and write mask), [nkq,2*nkq) convert Q.
// ---------------------------------------------------------------------------
__global__ __launch_bounds__(256)
void convert_frag(const float* __restrict__ Qg, const float* __restrict__ Kg,
                  unsigned char* __restrict__ ws, int nkq) {
  int bx = blockIdx.x;
  const bool isQ = (bx >= nkq);
  const int t = isQ ? bx - nkq : bx;       // batch*NT + kt
  const int batch = t >> 5, kt = t & 31;
  const float* sp = (isQ ? Qg : Kg) + (size_t)batch * NK * ND + kt * BK;
  unsigned char* dp = ws + (isQ ? WS_Q_OFF : 0) + (size_t)t * TILE_BYTES;
  float* maskB = (float*)(ws + WS_K) + batch * NK;
#pragma unroll
  for (int it = 0; it < 8; ++it) {
    int s = threadIdx.x + 256 * it;        // 2048 frag slots
    int g16 = s >> 6, t6 = s & 63;
    int l = ((t6 & 3) << 4) | ((t6 >> 2) & 15);   // permuted slot
    int row = g16 * 16 + (l & 15);                // = g16*16 + (t6>>2)&15
    int j0 = (l >> 4) * 8;                        // = (t6&3)*8
    const float* p = sp + (size_t)row * ND + j0;
    float4 v0 = *(const float4*)p;
    float4 v1 = *(const float4*)(p + 4);
    short8 hi8, lo8;
    cvt8(v0, v1, hi8, lo8);
    *(short8*)(dp + g16 * 2048 + l * 16) = hi8;
    *(short8*)(dp + g16 * 2048 + 1024 + l * 16) = lo8;
    if (!isQ && kt == 0 && j0 == 0) maskB[row] = v0.x;   // K[b][row][0]
  }
}

// ---------------------------------------------------------------------------
// K-loop helpers: by-ref fixed arrays, constant indices after inlining.
// ---------------------------------------------------------------------------
__device__ __forceinline__ void load_ab(const unsigned char* tq,
                                        const unsigned char* tk,
                                        int qg0, int w, int ln,
                                        short8 (&AH)[4], short8 (&AL)[4],
                                        short8 (&BH)[4], short8 (&BL)[4]) {
#pragma unroll
  for (int i = 0; i < 4; ++i) {
    const unsigned char* fa = tq + (qg0 + i) * 2048 + ln * 16;
    AH[i] = *(const short8*)fa;
    AL[i] = *(const short8*)(fa + 1024);
    const unsigned char* fb = tk + (w * 4 + i) * 2048 + ln * 16;
    BH[i] = *(const short8*)fb;
    BL[i] = *(const short8*)(fb + 1024);
  }
}
__device__ __forceinline__ void load_b(const unsigned char* tk, int w, int ln,
                                       short8 (&BH)[4], short8 (&BL)[4]) {
#pragma unroll
  for (int i = 0; i < 4; ++i) {
    const unsigned char* fb = tk + (w * 4 + i) * 2048 + ln * 16;
    BH[i] = *(const short8*)fb;
    BL[i] = *(const short8*)(fb + 1024);
  }
}
__device__ __forceinline__ void mfma_tile(const short8 (&AH)[4], const short8 (&AL)[4],
                                          const short8 (&BH)[4], const short8 (&BL)[4],
                                          f32x4 (&acc)[4][4]) {
#pragma unroll
  for (int nt = 0; nt < 4; ++nt)
#pragma unroll
    for (int mt = 0; mt < 4; ++mt)
      acc[mt][nt] = __builtin_amdgcn_mfma_f32_16x16x32_bf16(AH[mt], BH[nt], acc[mt][nt], 0, 0, 0);
#pragma unroll
  for (int nt = 0; nt < 4; ++nt)
#pragma unroll
    for (int mt = 0; mt < 4; ++mt)
      acc[mt][nt] = __builtin_amdgcn_mfma_f32_16x16x32_bf16(AH[mt], BL[nt], acc[mt][nt], 0, 0, 0);
#pragma unroll
  for (int nt = 0; nt < 4; ++nt)
#pragma unroll
    for (int mt = 0; mt < 4; ++mt)
      acc[mt][nt] = __builtin_amdgcn_mfma_f32_16x16x32_bf16(AL[mt], BH[nt], acc[mt][nt], 0, 0, 0);
}

// ---------------------------------------------------------------------------
// Shared epilogue: mask + softmax + attn + confidence.
// acc layout: row = mt*16 + quad*4 + rg (block-local), col = col0 + nt*16 + ln15
// ---------------------------------------------------------------------------
__device__ __forceinline__ void softmax_epilogue(
    f32x4 (&acc)[4][4], float (*sRedA)[64], float (*sRedB)[64],
    const float* maskB, const float* Tp, const float* Bp,
    float* __restrict__ attn, float* __restrict__ conf,
    int batch, int q0, int w, int ln15, int quad, int col0) {
  const float NEGINF = -__builtin_inff();
  float rm[4][4];
#pragma unroll
  for (int mt = 0; mt < 4; ++mt)
#pragma unroll
    for (int rg = 0; rg < 4; ++rg) rm[mt][rg] = NEGINF;

#pragma unroll
  for (int nt = 0; nt < 4; ++nt) {
    int col = col0 + nt * 16 + ln15;
    bool msk = (maskB[col] == 0.0f);
#pragma unroll
    for (int mt = 0; mt < 4; ++mt)
#pragma unroll
      for (int rg = 0; rg < 4; ++rg) {
        float v = msk ? NEGINF : acc[mt][nt][rg];
        acc[mt][nt][rg] = v;
        rm[mt][rg] = fmaxf(rm[mt][rg], v);
      }
  }
#pragma unroll
  for (int mt = 0; mt < 4; ++mt)
#pragma unroll
    for (int rg = 0; rg < 4; ++rg) {
      float v = rm[mt][rg];
#pragma unroll
      for (int d = 1; d < 16; d <<= 1) v = fmaxf(v, __shfl_xor(v, d, 64));
      rm[mt][rg] = v;
    }
  if (ln15 == 0) {
#pragma unroll
    for (int mt = 0; mt < 4; ++mt)
#pragma unroll
      for (int rg = 0; rg < 4; ++rg)
        sRedA[w][mt * 16 + quad * 4 + rg] = rm[mt][rg];
  }
  __syncthreads();

  float gmax[4][4], gsum[4][4];
#pragma unroll
  for (int mt = 0; mt < 4; ++mt)
#pragma unroll
    for (int rg = 0; rg < 4; ++rg) {
      int row = mt * 16 + quad * 4 + rg;
      float m = sRedA[0][row];
#pragma unroll
      for (int c = 1; c < 8; ++c) m = fmaxf(m, sRedA[c][row]);
      gmax[mt][rg] = m;
      gsum[mt][rg] = 0.f;
    }

#pragma unroll
  for (int nt = 0; nt < 4; ++nt)
#pragma unroll
    for (int mt = 0; mt < 4; ++mt)
#pragma unroll
      for (int rg = 0; rg < 4; ++rg) {
        float e = __expf(acc[mt][nt][rg] - gmax[mt][rg]);
        acc[mt][nt][rg] = e;
        gsum[mt][rg] += e;
      }
#pragma unroll
  for (int mt = 0; mt < 4; ++mt)
#pragma unroll
    for (int rg = 0; rg < 4; ++rg) {
      float v = gsum[mt][rg];
#pragma unroll
      for (int d = 1; d < 16; d <<= 1) v += __shfl_xor(v, d, 64);
      gsum[mt][rg] = v;
    }
  if (ln15 == 0) {
#pragma unroll
    for (int mt = 0; mt < 4; ++mt)
#pragma unroll
      for (int rg = 0; rg < 4; ++rg)
        sRedB[w][mt * 16 + quad * 4 + rg] = gsum[mt][rg];
  }
  __syncthreads();
#pragma unroll
  for (int mt = 0; mt < 4; ++mt)
#pragma unroll
    for (int rg = 0; rg < 4; ++rg) {
      int row = mt * 16 + quad * 4 + rg;
      float s = sRedB[0][row];
#pragma unroll
      for (int c = 1; c < 8; ++c) s += sRedB[c][row];
      gsum[mt][rg] = s;
    }

  float* outBase = attn + ((size_t)batch * NQ + q0) * NK;
#pragma unroll
  for (int mt = 0; mt < 4; ++mt)
#pragma unroll
    for (int rg = 0; rg < 4; ++rg) {
      int row = mt * 16 + quad * 4 + rg;
      float inv = 1.0f / gsum[mt][rg];
#pragma unroll
      for (int nt = 0; nt < 4; ++nt)
        outBase[(size_t)row * NK + col0 + nt * 16 + ln15] = acc[mt][nt][rg] * inv;
    }

  if (w == 0 && ln15 == 0) {
    float tv = Tp[0], bv = Bp[0];
#pragma unroll
    for (int mt = 0; mt < 4; ++mt)
#pragma unroll
      for (int rg = 0; rg < 4; ++rg) {
        int row = mt * 16 + quad * 4 + rg;
        float lse = gmax[mt][rg] + __logf(gsum[mt][rg]);
        float t = (lse + bv) * tv;
        conf[(size_t)batch * NQ + q0 + row] = 1.0f / (1.0f + __expf(-t));
      }
  }
}

// ---------------------------------------------------------------------------
// attn_v5: Q and K both pre-converted; pure load+MFMA K-loop, named dbuf.
// ---------------------------------------------------------------------------
__global__ __launch_bounds__(512, 2)
void attn_v5(const unsigned char* __restrict__ ws,
             const float* __restrict__ Tp, const float* __restrict__ Bp,
             float* __restrict__ attn, float* __restrict__ conf) {
  __shared__ float sRedA[8][64];
  __shared__ float sRedB[8][64];

  const int tid = threadIdx.x;
  const int g = blockIdx.x;                 // 0..255
  const int batch = (g & 7) | (((g >> 3) & 3) << 3);   // co-XCD per batch
  const int q0 = (g >> 5) * 64;
  const int ln = tid & 63, w = tid >> 6;
  const int ln15 = ln & 15, quad = ln >> 4;
  const int col0 = w * 64;
  const int qg0 = (g >> 5) * 4;             // q-group base (16-row groups)

  const unsigned char* wsK = ws + (size_t)batch * NT * TILE_BYTES;
  const unsigned char* wsQ = ws + WS_Q_OFF + (size_t)batch * NT * TILE_BYTES;
  const float* maskB = (const float*)(ws + WS_K) + batch * NK;

  f32x4 acc[4][4];
#pragma unroll
  for (int mt = 0; mt < 4; ++mt)
#pragma unroll
    for (int nt = 0; nt < 4; ++nt) acc[mt][nt] = (f32x4){0.f, 0.f, 0.f, 0.f};

  short8 a0H[4], a0L[4], b0H[4], b0L[4];
  short8 a1H[4], a1L[4], b1H[4], b1L[4];

  load_ab(wsQ, wsK, qg0, w, ln, a0H, a0L, b0H, b0L);

  for (int kt = 0; kt < NT; kt += 2) {
    // prefetch kt+1 into buf1 (NT even -> kt+1 always valid)
    load_ab(wsQ + (size_t)(kt + 1) * TILE_BYTES,
            wsK + (size_t)(kt + 1) * TILE_BYTES, qg0, w, ln,
            a1H, a1L, b1H, b1L);
    mfma_tile(a0H, a0L, b0H, b0L, acc);      // waits only buf0's (older) loads
    if (kt + 2 < NT)
      load_ab(wsQ + (size_t)(kt + 2) * TILE_BYTES,
              wsK + (size_t)(kt + 2) * TILE_BYTES, qg0, w, ln,
              a0H, a0L, b0H, b0L);
    mfma_tile(a1H, a1L, b1H, b1L, acc);
  }

  softmax_epilogue(acc, sRedA, sRedB, maskB, Tp, Bp, attn, conf,
                   batch, q0, w, ln15, quad, col0);
}

// ---------------------------------------------------------------------------
// attn_v5k: K pre-converted only; A loaded fp32 + converted in-register.
// ---------------------------------------------------------------------------
__device__ __forceinline__ void load_a_raw(const float* Qbase, int kt,
                                           int ln15, int quad, float4 (&raw)[8]) {
  const float* pA = Qbase + (size_t)ln15 * ND + kt * BK + quad * 8;
#pragma unroll
  for (int mt = 0; mt < 4; ++mt) {
    const float* p = pA + (size_t)mt * 16 * ND;
    raw[mt * 2] = *(const float4*)p;
    raw[mt * 2 + 1] = *(const float4*)(p + 4);
  }
}
__device__ __forceinline__ void cvt_a(const float4 (&raw)[8],
                                      short8 (&AH)[4], short8 (&AL)[4]) {
#pragma unroll
  for (int mt = 0; mt < 4; ++mt)
    cvt8(raw[mt * 2], raw[mt * 2 + 1], AH[mt], AL[mt]);
}

__global__ __launch_bounds__(512, 2)
void attn_v5k(const float* __restrict__ Qg, const unsigned char* __restrict__ ws,
              const float* __restrict__ Tp, const float* __restrict__ Bp,
              float* __restrict__ attn, float* __restrict__ conf) {
  __shared__ float sRedA[8][64];
  __shared__ float sRedB[8][64];

  const int tid = threadIdx.x;
  const int g = blockIdx.x;
  const int batch = (g & 7) | (((g >> 3) & 3) << 3);
  const int q0 = (g >> 5) * 64;
  const int ln = tid & 63, w = tid >> 6;
  const int ln15 = ln & 15, quad = ln >> 4;
  const int col0 = w * 64;

  const unsigned char* wsK = ws + (size_t)batch * NT * TILE_BYTES;
  const float* maskB = (const float*)(ws + WS_K) + batch * NK;
  const float* Qbase = Qg + ((size_t)batch * NQ + q0) * ND;

  f32x4 acc[4][4];
#pragma unroll
  for (int mt = 0; mt < 4; ++mt)
#pragma unroll
    for (int nt = 0; nt < 4; ++nt) acc[mt][nt] = (f32x4){0.f, 0.f, 0.f, 0.f};

  float4 raw[8];
  short8 a0H[4], a0L[4], a1H[4], a1L[4];
  short8 b0H[4], b0L[4], b1H[4], b1L[4];

  load_a_raw(Qbase, 0, ln15, quad, raw);
  load_b(wsK, w, ln, b0H, b0L);
  cvt_a(raw, a0H, a0L);

  for (int kt = 0; kt < NT; kt += 2) {
    load_a_raw(Qbase, kt + 1, ln15, quad, raw);
    load_b(wsK + (size_t)(kt + 1) * TILE_BYTES, w, ln, b1H, b1L);
    mfma_tile(a0H, a0L, b0H, b0L, acc);
    cvt_a(raw, a1H, a1L);                       // raw(kt+1) drained under MFMA
    if (kt + 2 < NT) {
      load_a_raw(Qbase, kt + 2, ln15, quad, raw);
      load_b(wsK + (size_t)(kt + 2) * TILE_BYTES, w, ln, b0H, b0L);
    }
    mfma_tile(a1H, a1L, b1H, b1L, acc);
    if (kt + 2 < NT) cvt_a(raw, a0H, a0L);
  }

  softmax_epilogue(acc, sRedA, sRedB, maskB, Tp, Bp, attn, conf,
                   batch, q0, w, ln15, quad, col0);
}

// ---------------------------------------------------------------------------
// Fallback: single-kernel path (no ws) — R1 structure.
// ---------------------------------------------------------------------------
__device__ __forceinline__ int lds_off_write(int r, int c4) {
  int slot = ((c4 >> 1) + (r >> 1)) & 3;
  return r * 32 + slot * 8 + (c4 & 1) * 4;
}
__device__ __forceinline__ int lds_off_read(int r, int quad) {
  int slot = (quad + (r >> 1)) & 3;
  return r * 32 + slot * 8;
}

__global__ __launch_bounds__(256, 1)
void attn_fused_v1(const float* __restrict__ Qg, const float* __restrict__ Kg,
                   const float* __restrict__ Tp, const float* __restrict__ Bp,
                   float* __restrict__ attn, float* __restrict__ conf) {
  __shared__ __align__(16) unsigned short sAhi[BM1 * BK];
  __shared__ __align__(16) unsigned short sAlo[BM1 * BK];
  __shared__ __align__(16) unsigned short sBhi[NK * BK];
  __shared__ __align__(16) unsigned short sBlo[NK * BK];
  __shared__ float sRedA[4][BM1];
  __shared__ float sRedB[4][BM1];

  const int tid = threadIdx.x;
  const int g = blockIdx.x;
  const int batch = (g & 7) | (((g >> 3) & 3) << 3);
  const int q0 = (g >> 5) * BM1;
  const int ln = tid & 63, w = tid >> 6;
  const int ln15 = ln & 15, quad = ln >> 4;
  const int wn0 = w * 128;

  const float* Qp = Qg + ((size_t)batch * NQ + q0) * ND;
  const float* Kp = Kg + (size_t)batch * NK * ND;

  f32x4 acc[4][8];
#pragma unroll
  for (int mt = 0; mt < 4; ++mt)
#pragma unroll
    for (int nt = 0; nt < 8; ++nt) acc[mt][nt] = (f32x4){0.f, 0.f, 0.f, 0.f};

  float4 pb[16], pa[2];
#pragma unroll
  for (int i = 0; i < 16; ++i) {
    int idx = tid + 256 * i, r = idx >> 3, c4 = idx & 7;
    pb[i] = *(const float4*)(Kp + (size_t)r * ND + c4 * 4);
  }
#pragma unroll
  for (int i = 0; i < 2; ++i) {
    int idx = tid + 256 * i, r = idx >> 3, c4 = idx & 7;
    pa[i] = *(const float4*)(Qp + (size_t)r * ND + c4 * 4);
  }

  for (int kt = 0; kt < NT; ++kt) {
    if (kt) __syncthreads();
#pragma unroll
    for (int i = 0; i < 2; ++i) {
      int idx = tid + 256 * i, r = idx >> 3, c4 = idx & 7;
      int off = lds_off_write(r, c4);
      unsigned h0, h1, h2, h3; float l0, l1, l2, l3;
      bf_split(pa[i].x, h0, l0); bf_split(pa[i].y, h1, l1);
      bf_split(pa[i].z, h2, l2); bf_split(pa[i].w, h3, l3);
      *(uint2*)(&sAhi[off]) = make_uint2((h0 >> 16) | h1, (h2 >> 16) | h3);
      *(uint2*)(&sAlo[off]) = make_uint2(pack_rn(l0, l1), pack_rn(l2, l3));
    }
#pragma unroll
    for (int i = 0; i < 16; ++i) {
      int idx = tid + 256 * i, r = idx >> 3, c4 = idx & 7;
      int off = lds_off_write(r, c4);
      unsigned h0, h1, h2, h3; float l0, l1, l2, l3;
      bf_split(pb[i].x, h0, l0); bf_split(pb[i].y, h1, l1);
      bf_split(pb[i].z, h2, l2); bf_split(pb[i].w, h3, l3);
      *(uint2*)(&sBhi[off]) = make_uint2((h0 >> 16) | h1, (h2 >> 16) | h3);
      *(uint2*)(&sBlo[off]) = make_uint2(pack_rn(l0, l1), pack_rn(l2, l3));
    }
    __syncthreads();

    if (kt < NT - 1) {
      const float* Kq = Kp + (kt + 1) * BK;
      const float* Qq = Qp + (kt + 1) * BK;
#pragma unroll
      for (int i = 0; i < 16; ++i) {
        int idx = tid + 256 * i, r = idx >> 3, c4 = idx & 7;
        pb[i] = *(const float4*)(Kq + (size_t)r * ND + c4 * 4);
      }
#pragma unroll
      for (int i = 0; i < 2; ++i) {
        int idx = tid + 256 * i, r = idx >> 3, c4 = idx & 7;
        pa[i] = *(const float4*)(Qq + (size_t)r * ND + c4 * 4);
      }
    }

    short8 ahi[4], alo[4];
#pragma unroll
    for (int mt = 0; mt < 4; ++mt) {
      int off = lds_off_read(mt * 16 + ln15, quad);
      ahi[mt] = *(const short8*)(&sAhi[off]);
      alo[mt] = *(const short8*)(&sAlo[off]);
    }
#pragma unroll
    for (int nt = 0; nt < 8; ++nt) {
      int off = lds_off_read(wn0 + nt * 16 + ln15, quad);
      short8 bhi = *(const short8*)(&sBhi[off]);
      short8 blo = *(const short8*)(&sBlo[off]);
#pragma unroll
      for (int mt = 0; mt < 4; ++mt) {
        acc[mt][nt] = __builtin_amdgcn_mfma_f32_16x16x32_bf16(ahi[mt], bhi, acc[mt][nt], 0, 0, 0);
        acc[mt][nt] = __builtin_amdgcn_mfma_f32_16x16x32_bf16(ahi[mt], blo, acc[mt][nt], 0, 0, 0);
        acc[mt][nt] = __builtin_amdgcn_mfma_f32_16x16x32_bf16(alo[mt], bhi, acc[mt][nt], 0, 0, 0);
      }
    }
  }

  const float NEGINF = -__builtin_inff();
  float rm[4][4];
#pragma unroll
  for (int mt = 0; mt < 4; ++mt)
#pragma unroll
    for (int rg = 0; rg < 4; ++rg) rm[mt][rg] = NEGINF;
#pragma unroll
  for (int nt = 0; nt < 8; ++nt) {
    int col = wn0 + nt * 16 + ln15;
    bool msk = (Kp[(size_t)col * ND] == 0.0f);
#pragma unroll
    for (int mt = 0; mt < 4; ++mt)
#pragma unroll
      for (int rg = 0; rg < 4; ++rg) {
        float v = msk ? NEGINF : acc[mt][nt][rg];
        acc[mt][nt][rg] = v;
        rm[mt][rg] = fmaxf(rm[mt][rg], v);
      }
  }
#pragma unroll
  for (int mt = 0; mt < 4; ++mt)
#pragma unroll
    for (int rg = 0; rg < 4; ++rg) {
      float v = rm[mt][rg];
#pragma unroll
      for (int d = 1; d < 16; d <<= 1) v = fmaxf(v, __shfl_xor(v, d, 64));
      rm[mt][rg] = v;
    }
  if (ln15 == 0)
#pragma unroll
    for (int mt = 0; mt < 4; ++mt)
#pragma unroll
      for (int rg = 0; rg < 4; ++rg)
        sRedA[w][mt * 16 + quad * 4 + rg] = rm[mt][rg];
  __syncthreads();

  float gmax[4][4], gsum[4][4];
#pragma unroll
  for (int mt = 0; mt < 4; ++mt)
#pragma unroll
    for (int rg = 0; rg < 4; ++rg) {
      int row = mt * 16 + quad * 4 + rg;
      gmax[mt][rg] = fmaxf(fmaxf(sRedA[0][row], sRedA[1][row]),
                           fmaxf(sRedA[2][row], sRedA[3][row]));
      gsum[mt][rg] = 0.f;
    }
#pragma unroll
  for (int nt = 0; nt < 8; ++nt)
#pragma unroll
    for (int mt = 0; mt < 4; ++mt)
#pragma unroll
      for (int rg = 0; rg < 4; ++rg) {
        float e = __expf(acc[mt][nt][rg] - gmax[mt][rg]);
        acc[mt][nt][rg] = e;
        gsum[mt][rg] += e;
      }
#pragma unroll
  for (int mt = 0; mt < 4; ++mt)
#pragma unroll
    for (int rg = 0; rg < 4; ++rg) {
      float v = gsum[mt][rg];
#pragma unroll
      for (int d = 1; d < 16; d <<= 1) v += __shfl_xor(v, d, 64);
      gsum[mt][rg] = v;
    }
  if (ln15 == 0)
#pragma unroll
    for (int mt = 0; mt < 4; ++mt)
#pragma unroll
      for (int rg = 0; rg < 4; ++rg)
        sRedB[w][mt * 16 + quad * 4 + rg] = gsum[mt][rg];
  __syncthreads();
#pragma unroll
  for (int mt = 0; mt < 4; ++mt)
#pragma unroll
    for (int rg = 0; rg < 4; ++rg) {
      int row = mt * 16 + quad * 4 + rg;
      gsum[mt][rg] = sRedB[0][row] + sRedB[1][row] + sRedB[2][row] + sRedB[3][row];
    }

  float* outBase = attn + ((size_t)batch * NQ + q0) * NK;
#pragma unroll
  for (int mt = 0; mt < 4; ++mt)
#pragma unroll
    for (int rg = 0; rg < 4; ++rg) {
      int row = mt * 16 + quad * 4 + rg;
      float inv = 1.0f / gsum[mt][rg];
#pragma unroll
      for (int nt = 0; nt < 8; ++nt)
        outBase[(size_t)row * NK + wn0 + nt * 16 + ln15] = acc[mt][nt][rg] * inv;
    }
  if (w == 0 && ln15 == 0) {
    float tv = Tp[0], bv = Bp[0];
#pragma unroll
    for (int mt = 0; mt < 4; ++mt)
#pragma unroll
      for (int rg = 0; rg < 4; ++rg) {
        int row = mt * 16 + quad * 4 + rg;
        float lse = gmax[mt][rg] + __logf(gsum[mt][rg]);
        float t = (lse + bv) * tv;
        conf[(size_t)batch * NQ + q0 + row] = 1.0f / (1.0f + __expf(-t));
      }
  }
}

extern "C" void kernel_launch(void* const* d_in, const int* in_sizes, int n_in,
                              void* d_out, int out_size, void* d_ws, size_t ws_size,
                              hipStream_t stream) {
  const float* q = (const float*)d_in[0];
  const float* k = (const float*)d_in[1];
  const float* temp = (const float*)d_in[2];
  const float* bias = (const float*)d_in[3];
  float* attn = (float*)d_out;
  float* conf = attn + (size_t)NB * NQ * NK;

  if (ws_size >= WS_V5) {
    hipLaunchKernelGGL(convert_frag, dim3(2 * NB * NT), dim3(256), 0, stream,
                       q, k, (unsigned char*)d_ws, NB * NT);
    hipLaunchKernelGGL(attn_v5, dim3(256), dim3(512), 0, stream,
                       (const unsigned char*)d_ws, temp, bias, attn, conf);
  } else if (ws_size >= WS_V5K) {
    hipLaunchKernelGGL(convert_frag, dim3(NB * NT), dim3(256), 0, stream,
                       q, k, (unsigned char*)d_ws, NB * NT);
    hipLaunchKernelGGL(attn_v5k, dim3(256), dim3(512), 0, stream,
                       q, (const unsigned char*)d_ws, temp, bias, attn, conf);
  } else {
    hipLaunchKernelGGL(attn_fused_v1, dim3(NB * (NQ / BM1)), dim3(256), 0, stream,
                       q, k, temp, bias, attn, conf);
  }
}

// Round 7
// 234.741 us; speedup vs baseline: 1.0092x; 1.0092x over previous
//
#include <hip/hip_runtime.h>
#include <math.h>
#include <stdint.h>

// ContentAttention fused, round 7.
// R5/R6 post-mortem pair: converter ran 83us both with coalesced-writes+
// scattered-reads (R5) and coalesced-reads+scattered-writes (R6) -> one
// scattered side costs the same either way; permuted full covers do NOT
// merge in the store coalescer. R7 stages the transpose through LDS:
//   phase 1: coalesced fp32 reads (128B row runs) -> convert -> LDS scatter
//            (byte-identical 32KB image of the ws fragment slab)
//   phase 2: barrier -> lane-contiguous ds_read_b128 -> perfectly coalesced
//            1KB-per-instruction global stores.
// Half-tile per block (32KB LDS, 5 blocks/CU), grid 4096.
// attn_v5 (named-dbuf fragment-order GEMM, ~50us) unchanged.

#define NB 32
#define NQ 512
#define NK 512
#define ND 1024
#define BK 32
#define NT (ND / BK)            // 32 k-tiles
#define BM1 64                  // fallback rows/block
#define TILE_BYTES 65536        // per (batch,kt): 32 groups x (1KB hi + 1KB lo)
#define WS_K ((size_t)NB * NT * TILE_BYTES)       // 64 MiB K fragment image
#define MASK_BYTES ((size_t)NB * NK * 4)          // 64 KiB
#define WS_Q_OFF (WS_K + MASK_BYTES)
#define WS_V5 (WS_Q_OFF + WS_K)                   // + 64 MiB Q fragment image
#define WS_V5K (WS_K + MASK_BYTES)

typedef __attribute__((ext_vector_type(8))) short short8;
typedef __attribute__((ext_vector_type(4))) float f32x4;

__device__ __forceinline__ void bf_split(float x, unsigned& hbits, float& lo) {
  unsigned u = __float_as_uint(x);
  unsigned r = u + 0x7fffu + ((u >> 16) & 1u);
  hbits = r & 0xffff0000u;
  lo = x - __uint_as_float(hbits);
}
__device__ __forceinline__ unsigned pack_rn(float x0, float x1) {
  unsigned u0 = __float_as_uint(x0), u1 = __float_as_uint(x1);
  unsigned r0 = u0 + 0x7fffu + ((u0 >> 16) & 1u);
  unsigned r1 = u1 + 0x7fffu + ((u1 >> 16) & 1u);
  return (r0 >> 16) | (r1 & 0xffff0000u);
}

// 8 fp32 -> bf16-hi frag + bf16-lo frag (each 8 bf16 = 16 B).
__device__ __forceinline__ void cvt8(const float4& v0, const float4& v1,
                                     short8& hi8, short8& lo8) {
  float f[8] = {v0.x, v0.y, v0.z, v0.w, v1.x, v1.y, v1.z, v1.w};
  unsigned hh[8];
  float ll[8];
#pragma unroll
  for (int i = 0; i < 8; ++i) bf_split(f[i], hh[i], ll[i]);
  union { uint4 u; short8 s; } H, L;
  H.u = make_uint4((hh[0] >> 16) | (hh[1] & 0xffff0000u),
                   (hh[2] >> 16) | (hh[3] & 0xffff0000u),
                   (hh[4] >> 16) | (hh[5] & 0xffff0000u),
                   (hh[6] >> 16) | (hh[7] & 0xffff0000u));
  L.u = make_uint4(pack_rn(ll[0], ll[1]), pack_rn(ll[2], ll[3]),
                   pack_rn(ll[4], ll[5]), pack_rn(ll[6], ll[7]));
  hi8 = H.s;
  lo8 = L.s;
}

// ---------------------------------------------------------------------------
// convert_frag_v7: fp32 -> MFMA fragment order via LDS-staged transpose.
// Fragment slot (g16, l): M[row = g16*16 + (l&15)][kt*32 + (l>>4)*8 + j].
// One block handles HALF a (batch,kt) tile: 256 rows -> 32 KB image.
// Grid 2*nhalfK: [0,nhalfK) = K halves (+ mask), [nhalfK,..) = Q halves.
// ---------------------------------------------------------------------------
__global__ __launch_bounds__(256)
void convert_frag_v7(const float* __restrict__ Qg, const float* __restrict__ Kg,
                     unsigned char* __restrict__ ws, int nhalfK) {
  __shared__ __align__(16) unsigned char sTile[32768];
  int bx = blockIdx.x;
  const bool isQ = (bx >= nhalfK);
  const int t2 = isQ ? bx - nhalfK : bx;
  const int t = t2 >> 1, h = t2 & 1;        // tile index, half index
  const int batch = t >> 5, kt = t & 31;
  const float* sp = (isQ ? Qg : Kg) + (size_t)batch * NK * ND + kt * BK;
  unsigned char* dp = ws + (isQ ? WS_Q_OFF : 0) + (size_t)t * TILE_BYTES
                      + (size_t)h * 32768;
  float* maskB = (float*)(ws + WS_K) + batch * NK;

  const int tid = threadIdx.x;
  const int rl0 = tid >> 3, c4 = tid & 7;   // 8 threads span one row's 32 cols

  // phase 1: coalesced global read (128B row runs) -> convert -> LDS scatter
#pragma unroll
  for (int i = 0; i < 8; ++i) {
    int rl = i * 32 + rl0;                  // local row 0..255
    int r = h * 256 + rl;                   // tile row
    float4 v = *(const float4*)(sp + (size_t)r * ND + c4 * 4);
    unsigned h0, h1, h2, h3;
    float l0, l1, l2, l3;
    bf_split(v.x, h0, l0); bf_split(v.y, h1, l1);
    bf_split(v.z, h2, l2); bf_split(v.w, h3, l3);
    int l = (rl & 15) | ((c4 >> 1) << 4);   // frag lane for these 4 elems
    int base = (rl >> 4) * 2048 + l * 16 + (c4 & 1) * 8;
    *(uint2*)(sTile + base) =
        make_uint2((h0 >> 16) | h1, (h2 >> 16) | h3);
    *(uint2*)(sTile + base + 1024) =
        make_uint2(pack_rn(l0, l1), pack_rn(l2, l3));
    if (!isQ && kt == 0 && c4 == 0) maskB[r] = v.x;   // K[b][r][0]
  }
  __syncthreads();

  // phase 2: lane-contiguous LDS read -> coalesced 1KB global stores
#pragma unroll
  for (int i = 0; i < 8; ++i) {
    int c = i * 256 + tid;                  // 2048 16B chunks
    *(uint4*)(dp + (size_t)c * 16) = *(const uint4*)(sTile + c * 16);
  }
}

// ---------------------------------------------------------------------------
// K-loop helpers: by-ref fixed arrays, constant indices after inlining.
// ---------------------------------------------------------------------------
__device__ __forceinline__ void load_ab(const unsigned char* tq,
                                        const unsigned char* tk,
                                        int qg0, int w, int ln,
                                        short8 (&AH)[4], short8 (&AL)[4],
                                        short8 (&BH)[4], short8 (&BL)[4]) {
#pragma unroll
  for (int i = 0; i < 4; ++i) {
    const unsigned char* fa = tq + (qg0 + i) * 2048 + ln * 16;
    AH[i] = *(const short8*)fa;
    AL[i] = *(const short8*)(fa + 1024);
    const unsigned char* fb = tk + (w * 4 + i) * 2048 + ln * 16;
    BH[i] = *(const short8*)fb;
    BL[i] = *(const short8*)(fb + 1024);
  }
}
__device__ __forceinline__ void load_b(const unsigned char* tk, int w, int ln,
                                       short8 (&BH)[4], short8 (&BL)[4]) {
#pragma unroll
  for (int i = 0; i < 4; ++i) {
    const unsigned char* fb = tk + (w * 4 + i) * 2048 + ln * 16;
    BH[i] = *(const short8*)fb;
    BL[i] = *(const short8*)(fb + 1024);
  }
}
__device__ __forceinline__ void mfma_tile(const short8 (&AH)[4], const short8 (&AL)[4],
                                          const short8 (&BH)[4], const short8 (&BL)[4],
                                          f32x4 (&acc)[4][4]) {
#pragma unroll
  for (int nt = 0; nt < 4; ++nt)
#pragma unroll
    for (int mt = 0; mt < 4; ++mt)
      acc[mt][nt] = __builtin_amdgcn_mfma_f32_16x16x32_bf16(AH[mt], BH[nt], acc[mt][nt], 0, 0, 0);
#pragma unroll
  for (int nt = 0; nt < 4; ++nt)
#pragma unroll
    for (int mt = 0; mt < 4; ++mt)
      acc[mt][nt] = __builtin_amdgcn_mfma_f32_16x16x32_bf16(AH[mt], BL[nt], acc[mt][nt], 0, 0, 0);
#pragma unroll
  for (int nt = 0; nt < 4; ++nt)
#pragma unroll
    for (int mt = 0; mt < 4; ++mt)
      acc[mt][nt] = __builtin_amdgcn_mfma_f32_16x16x32_bf16(AL[mt], BH[nt], acc[mt][nt], 0, 0, 0);
}

// ---------------------------------------------------------------------------
// Shared epilogue: mask + softmax + attn + confidence.
// acc layout: row = mt*16 + quad*4 + rg (block-local), col = col0 + nt*16 + ln15
// ---------------------------------------------------------------------------
__device__ __forceinline__ void softmax_epilogue(
    f32x4 (&acc)[4][4], float (*sRedA)[64], float (*sRedB)[64],
    const float* maskB, const float* Tp, const float* Bp,
    float* __restrict__ attn, float* __restrict__ conf,
    int batch, int q0, int w, int ln15, int quad, int col0) {
  const float NEGINF = -__builtin_inff();
  float rm[4][4];
#pragma unroll
  for (int mt = 0; mt < 4; ++mt)
#pragma unroll
    for (int rg = 0; rg < 4; ++rg) rm[mt][rg] = NEGINF;

#pragma unroll
  for (int nt = 0; nt < 4; ++nt) {
    int col = col0 + nt * 16 + ln15;
    bool msk = (maskB[col] == 0.0f);
#pragma unroll
    for (int mt = 0; mt < 4; ++mt)
#pragma unroll
      for (int rg = 0; rg < 4; ++rg) {
        float v = msk ? NEGINF : acc[mt][nt][rg];
        acc[mt][nt][rg] = v;
        rm[mt][rg] = fmaxf(rm[mt][rg], v);
      }
  }
#pragma unroll
  for (int mt = 0; mt < 4; ++mt)
#pragma unroll
    for (int rg = 0; rg < 4; ++rg) {
      float v = rm[mt][rg];
#pragma unroll
      for (int d = 1; d < 16; d <<= 1) v = fmaxf(v, __shfl_xor(v, d, 64));
      rm[mt][rg] = v;
    }
  if (ln15 == 0) {
#pragma unroll
    for (int mt = 0; mt < 4; ++mt)
#pragma unroll
      for (int rg = 0; rg < 4; ++rg)
        sRedA[w][mt * 16 + quad * 4 + rg] = rm[mt][rg];
  }
  __syncthreads();

  float gmax[4][4], gsum[4][4];
#pragma unroll
  for (int mt = 0; mt < 4; ++mt)
#pragma unroll
    for (int rg = 0; rg < 4; ++rg) {
      int row = mt * 16 + quad * 4 + rg;
      float m = sRedA[0][row];
#pragma unroll
      for (int c = 1; c < 8; ++c) m = fmaxf(m, sRedA[c][row]);
      gmax[mt][rg] = m;
      gsum[mt][rg] = 0.f;
    }

#pragma unroll
  for (int nt = 0; nt < 4; ++nt)
#pragma unroll
    for (int mt = 0; mt < 4; ++mt)
#pragma unroll
      for (int rg = 0; rg < 4; ++rg) {
        float e = __expf(acc[mt][nt][rg] - gmax[mt][rg]);
        acc[mt][nt][rg] = e;
        gsum[mt][rg] += e;
      }
#pragma unroll
  for (int mt = 0; mt < 4; ++mt)
#pragma unroll
    for (int rg = 0; rg < 4; ++rg) {
      float v = gsum[mt][rg];
#pragma unroll
      for (int d = 1; d < 16; d <<= 1) v += __shfl_xor(v, d, 64);
      gsum[mt][rg] = v;
    }
  if (ln15 == 0) {
#pragma unroll
    for (int mt = 0; mt < 4; ++mt)
#pragma unroll
      for (int rg = 0; rg < 4; ++rg)
        sRedB[w][mt * 16 + quad * 4 + rg] = gsum[mt][rg];
  }
  __syncthreads();
#pragma unroll
  for (int mt = 0; mt < 4; ++mt)
#pragma unroll
    for (int rg = 0; rg < 4; ++rg) {
      int row = mt * 16 + quad * 4 + rg;
      float s = sRedB[0][row];
#pragma unroll
      for (int c = 1; c < 8; ++c) s += sRedB[c][row];
      gsum[mt][rg] = s;
    }

  float* outBase = attn + ((size_t)batch * NQ + q0) * NK;
#pragma unroll
  for (int mt = 0; mt < 4; ++mt)
#pragma unroll
    for (int rg = 0; rg < 4; ++rg) {
      int row = mt * 16 + quad * 4 + rg;
      float inv = 1.0f / gsum[mt][rg];
#pragma unroll
      for (int nt = 0; nt < 4; ++nt)
        outBase[(size_t)row * NK + col0 + nt * 16 + ln15] = acc[mt][nt][rg] * inv;
    }

  if (w == 0 && ln15 == 0) {
    float tv = Tp[0], bv = Bp[0];
#pragma unroll
    for (int mt = 0; mt < 4; ++mt)
#pragma unroll
      for (int rg = 0; rg < 4; ++rg) {
        int row = mt * 16 + quad * 4 + rg;
        float lse = gmax[mt][rg] + __logf(gsum[mt][rg]);
        float t = (lse + bv) * tv;
        conf[(size_t)batch * NQ + q0 + row] = 1.0f / (1.0f + __expf(-t));
      }
  }
}

// ---------------------------------------------------------------------------
// attn_v5: Q and K both pre-converted; pure load+MFMA K-loop, named dbuf.
// ---------------------------------------------------------------------------
__global__ __launch_bounds__(512, 2)
void attn_v5(const unsigned char* __restrict__ ws,
             const float* __restrict__ Tp, const float* __restrict__ Bp,
             float* __restrict__ attn, float* __restrict__ conf) {
  __shared__ float sRedA[8][64];
  __shared__ float sRedB[8][64];

  const int tid = threadIdx.x;
  const int g = blockIdx.x;                 // 0..255
  const int batch = (g & 7) | (((g >> 3) & 3) << 3);   // co-XCD per batch
  const int q0 = (g >> 5) * 64;
  const int ln = tid & 63, w = tid >> 6;
  const int ln15 = ln & 15, quad = ln >> 4;
  const int col0 = w * 64;
  const int qg0 = (g >> 5) * 4;             // q-group base (16-row groups)

  const unsigned char* wsK = ws + (size_t)batch * NT * TILE_BYTES;
  const unsigned char* wsQ = ws + WS_Q_OFF + (size_t)batch * NT * TILE_BYTES;
  const float* maskB = (const float*)(ws + WS_K) + batch * NK;

  f32x4 acc[4][4];
#pragma unroll
  for (int mt = 0; mt < 4; ++mt)
#pragma unroll
    for (int nt = 0; nt < 4; ++nt) acc[mt][nt] = (f32x4){0.f, 0.f, 0.f, 0.f};

  short8 a0H[4], a0L[4], b0H[4], b0L[4];
  short8 a1H[4], a1L[4], b1H[4], b1L[4];

  load_ab(wsQ, wsK, qg0, w, ln, a0H, a0L, b0H, b0L);

  for (int kt = 0; kt < NT; kt += 2) {
    // prefetch kt+1 into buf1 (NT even -> kt+1 always valid)
    load_ab(wsQ + (size_t)(kt + 1) * TILE_BYTES,
            wsK + (size_t)(kt + 1) * TILE_BYTES, qg0, w, ln,
            a1H, a1L, b1H, b1L);
    mfma_tile(a0H, a0L, b0H, b0L, acc);      // waits only buf0's (older) loads
    if (kt + 2 < NT)
      load_ab(wsQ + (size_t)(kt + 2) * TILE_BYTES,
              wsK + (size_t)(kt + 2) * TILE_BYTES, qg0, w, ln,
              a0H, a0L, b0H, b0L);
    mfma_tile(a1H, a1L, b1H, b1L, acc);
  }

  softmax_epilogue(acc, sRedA, sRedB, maskB, Tp, Bp, attn, conf,
                   batch, q0, w, ln15, quad, col0);
}

// ---------------------------------------------------------------------------
// attn_v5k: K pre-converted only; A loaded fp32 + converted in-register.
// ---------------------------------------------------------------------------
__device__ __forceinline__ void load_a_raw(const float* Qbase, int kt,
                                           int ln15, int quad, float4 (&raw)[8]) {
  const float* pA = Qbase + (size_t)ln15 * ND + kt * BK + quad * 8;
#pragma unroll
  for (int mt = 0; mt < 4; ++mt) {
    const float* p = pA + (size_t)mt * 16 * ND;
    raw[mt * 2] = *(const float4*)p;
    raw[mt * 2 + 1] = *(const float4*)(p + 4);
  }
}
__device__ __forceinline__ void cvt_a(const float4 (&raw)[8],
                                      short8 (&AH)[4], short8 (&AL)[4]) {
#pragma unroll
  for (int mt = 0; mt < 4; ++mt)
    cvt8(raw[mt * 2], raw[mt * 2 + 1], AH[mt], AL[mt]);
}

__global__ __launch_bounds__(512, 2)
void attn_v5k(const float* __restrict__ Qg, const unsigned char* __restrict__ ws,
              const float* __restrict__ Tp, const float* __restrict__ Bp,
              float* __restrict__ attn, float* __restrict__ conf) {
  __shared__ float sRedA[8][64];
  __shared__ float sRedB[8][64];

  const int tid = threadIdx.x;
  const int g = blockIdx.x;
  const int batch = (g & 7) | (((g >> 3) & 3) << 3);
  const int q0 = (g >> 5) * 64;
  const int ln = tid & 63, w = tid >> 6;
  const int ln15 = ln & 15, quad = ln >> 4;
  const int col0 = w * 64;

  const unsigned char* wsK = ws + (size_t)batch * NT * TILE_BYTES;
  const float* maskB = (const float*)(ws + WS_K) + batch * NK;
  const float* Qbase = Qg + ((size_t)batch * NQ + q0) * ND;

  f32x4 acc[4][4];
#pragma unroll
  for (int mt = 0; mt < 4; ++mt)
#pragma unroll
    for (int nt = 0; nt < 4; ++nt) acc[mt][nt] = (f32x4){0.f, 0.f, 0.f, 0.f};

  float4 raw[8];
  short8 a0H[4], a0L[4], a1H[4], a1L[4];
  short8 b0H[4], b0L[4], b1H[4], b1L[4];

  load_a_raw(Qbase, 0, ln15, quad, raw);
  load_b(wsK, w, ln, b0H, b0L);
  cvt_a(raw, a0H, a0L);

  for (int kt = 0; kt < NT; kt += 2) {
    load_a_raw(Qbase, kt + 1, ln15, quad, raw);
    load_b(wsK + (size_t)(kt + 1) * TILE_BYTES, w, ln, b1H, b1L);
    mfma_tile(a0H, a0L, b0H, b0L, acc);
    cvt_a(raw, a1H, a1L);                       // raw(kt+1) drained under MFMA
    if (kt + 2 < NT) {
      load_a_raw(Qbase, kt + 2, ln15, quad, raw);
      load_b(wsK + (size_t)(kt + 2) * TILE_BYTES, w, ln, b0H, b0L);
    }
    mfma_tile(a1H, a1L, b1H, b1L, acc);
    if (kt + 2 < NT) cvt_a(raw, a0H, a0L);
  }

  softmax_epilogue(acc, sRedA, sRedB, maskB, Tp, Bp, attn, conf,
                   batch, q0, w, ln15, quad, col0);
}

// ---------------------------------------------------------------------------
// Fallback: single-kernel path (no ws) — R1 structure.
// ---------------------------------------------------------------------------
__device__ __forceinline__ int lds_off_write(int r, int c4) {
  int slot = ((c4 >> 1) + (r >> 1)) & 3;
  return r * 32 + slot * 8 + (c4 & 1) * 4;
}
__device__ __forceinline__ int lds_off_read(int r, int quad) {
  int slot = (quad + (r >> 1)) & 3;
  return r * 32 + slot * 8;
}

__global__ __launch_bounds__(256, 1)
void attn_fused_v1(const float* __restrict__ Qg, const float* __restrict__ Kg,
                   const float* __restrict__ Tp, const float* __restrict__ Bp,
                   float* __restrict__ attn, float* __restrict__ conf) {
  __shared__ __align__(16) unsigned short sAhi[BM1 * BK];
  __shared__ __align__(16) unsigned short sAlo[BM1 * BK];
  __shared__ __align__(16) unsigned short sBhi[NK * BK];
  __shared__ __align__(16) unsigned short sBlo[NK * BK];
  __shared__ float sRedA[4][BM1];
  __shared__ float sRedB[4][BM1];

  const int tid = threadIdx.x;
  const int g = blockIdx.x;
  const int batch = (g & 7) | (((g >> 3) & 3) << 3);
  const int q0 = (g >> 5) * BM1;
  const int ln = tid & 63, w = tid >> 6;
  const int ln15 = ln & 15, quad = ln >> 4;
  const int wn0 = w * 128;

  const float* Qp = Qg + ((size_t)batch * NQ + q0) * ND;
  const float* Kp = Kg + (size_t)batch * NK * ND;

  f32x4 acc[4][8];
#pragma unroll
  for (int mt = 0; mt < 4; ++mt)
#pragma unroll
    for (int nt = 0; nt < 8; ++nt) acc[mt][nt] = (f32x4){0.f, 0.f, 0.f, 0.f};

  float4 pb[16], pa[2];
#pragma unroll
  for (int i = 0; i < 16; ++i) {
    int idx = tid + 256 * i, r = idx >> 3, c4 = idx & 7;
    pb[i] = *(const float4*)(Kp + (size_t)r * ND + c4 * 4);
  }
#pragma unroll
  for (int i = 0; i < 2; ++i) {
    int idx = tid + 256 * i, r = idx >> 3, c4 = idx & 7;
    pa[i] = *(const float4*)(Qp + (size_t)r * ND + c4 * 4);
  }

  for (int kt = 0; kt < NT; ++kt) {
    if (kt) __syncthreads();
#pragma unroll
    for (int i = 0; i < 2; ++i) {
      int idx = tid + 256 * i, r = idx >> 3, c4 = idx & 7;
      int off = lds_off_write(r, c4);
      unsigned h0, h1, h2, h3; float l0, l1, l2, l3;
      bf_split(pa[i].x, h0, l0); bf_split(pa[i].y, h1, l1);
      bf_split(pa[i].z, h2, l2); bf_split(pa[i].w, h3, l3);
      *(uint2*)(&sAhi[off]) = make_uint2((h0 >> 16) | h1, (h2 >> 16) | h3);
      *(uint2*)(&sAlo[off]) = make_uint2(pack_rn(l0, l1), pack_rn(l2, l3));
    }
#pragma unroll
    for (int i = 0; i < 16; ++i) {
      int idx = tid + 256 * i, r = idx >> 3, c4 = idx & 7;
      int off = lds_off_write(r, c4);
      unsigned h0, h1, h2, h3; float l0, l1, l2, l3;
      bf_split(pb[i].x, h0, l0); bf_split(pb[i].y, h1, l1);
      bf_split(pb[i].z, h2, l2); bf_split(pb[i].w, h3, l3);
      *(uint2*)(&sBhi[off]) = make_uint2((h0 >> 16) | h1, (h2 >> 16) | h3);
      *(uint2*)(&sBlo[off]) = make_uint2(pack_rn(l0, l1), pack_rn(l2, l3));
    }
    __syncthreads();

    if (kt < NT - 1) {
      const float* Kq = Kp + (kt + 1) * BK;
      const float* Qq = Qp + (kt + 1) * BK;
#pragma unroll
      for (int i = 0; i < 16; ++i) {
        int idx = tid + 256 * i, r = idx >> 3, c4 = idx & 7;
        pb[i] = *(const float4*)(Kq + (size_t)r * ND + c4 * 4);
      }
#pragma unroll
      for (int i = 0; i < 2; ++i) {
        int idx = tid + 256 * i, r = idx >> 3, c4 = idx & 7;
        pa[i] = *(const float4*)(Qq + (size_t)r * ND + c4 * 4);
      }
    }

    short8 ahi[4], alo[4];
#pragma unroll
    for (int mt = 0; mt < 4; ++mt) {
      int off = lds_off_read(mt * 16 + ln15, quad);
      ahi[mt] = *(const short8*)(&sAhi[off]);
      alo[mt] = *(const short8*)(&sAlo[off]);
    }
#pragma unroll
    for (int nt = 0; nt < 8; ++nt) {
      int off = lds_off_read(wn0 + nt * 16 + ln15, quad);
      short8 bhi = *(const short8*)(&sBhi[off]);
      short8 blo = *(const short8*)(&sBlo[off]);
#pragma unroll
      for (int mt = 0; mt < 4; ++mt) {
        acc[mt][nt] = __builtin_amdgcn_mfma_f32_16x16x32_bf16(ahi[mt], bhi, acc[mt][nt], 0, 0, 0);
        acc[mt][nt] = __builtin_amdgcn_mfma_f32_16x16x32_bf16(ahi[mt], blo, acc[mt][nt], 0, 0, 0);
        acc[mt][nt] = __builtin_amdgcn_mfma_f32_16x16x32_bf16(alo[mt], bhi, acc[mt][nt], 0, 0, 0);
      }
    }
  }

  const float NEGINF = -__builtin_inff();
  float rm[4][4];
#pragma unroll
  for (int mt = 0; mt < 4; ++mt)
#pragma unroll
    for (int rg = 0; rg < 4; ++rg) rm[mt][rg] = NEGINF;
#pragma unroll
  for (int nt = 0; nt < 8; ++nt) {
    int col = wn0 + nt * 16 + ln15;
    bool msk = (Kp[(size_t)col * ND] == 0.0f);
#pragma unroll
    for (int mt = 0; mt < 4; ++mt)
#pragma unroll
      for (int rg = 0; rg < 4; ++rg) {
        float v = msk ? NEGINF : acc[mt][nt][rg];
        acc[mt][nt][rg] = v;
        rm[mt][rg] = fmaxf(rm[mt][rg], v);
      }
  }
#pragma unroll
  for (int mt = 0; mt < 4; ++mt)
#pragma unroll
    for (int rg = 0; rg < 4; ++rg) {
      float v = rm[mt][rg];
#pragma unroll
      for (int d = 1; d < 16; d <<= 1) v = fmaxf(v, __shfl_xor(v, d, 64));
      rm[mt][rg] = v;
    }
  if (ln15 == 0)
#pragma unroll
    for (int mt = 0; mt < 4; ++mt)
#pragma unroll
      for (int rg = 0; rg < 4; ++rg)
        sRedA[w][mt * 16 + quad * 4 + rg] = rm[mt][rg];
  __syncthreads();

  float gmax[4][4], gsum[4][4];
#pragma unroll
  for (int mt = 0; mt < 4; ++mt)
#pragma unroll
    for (int rg = 0; rg < 4; ++rg) {
      int row = mt * 16 + quad * 4 + rg;
      gmax[mt][rg] = fmaxf(fmaxf(sRedA[0][row], sRedA[1][row]),
                           fmaxf(sRedA[2][row], sRedA[3][row]));
      gsum[mt][rg] = 0.f;
    }
#pragma unroll
  for (int nt = 0; nt < 8; ++nt)
#pragma unroll
    for (int mt = 0; mt < 4; ++mt)
#pragma unroll
      for (int rg = 0; rg < 4; ++rg) {
        float e = __expf(acc[mt][nt][rg] - gmax[mt][rg]);
        acc[mt][nt][rg] = e;
        gsum[mt][rg] += e;
      }
#pragma unroll
  for (int mt = 0; mt < 4; ++mt)
#pragma unroll
    for (int rg = 0; rg < 4; ++rg) {
      float v = gsum[mt][rg];
#pragma unroll
      for (int d = 1; d < 16; d <<= 1) v += __shfl_xor(v, d, 64);
      gsum[mt][rg] = v;
    }
  if (ln15 == 0)
#pragma unroll
    for (int mt = 0; mt < 4; ++mt)
#pragma unroll
      for (int rg = 0; rg < 4; ++rg)
        sRedB[w][mt * 16 + quad * 4 + rg] = gsum[mt][rg];
  __syncthreads();
#pragma unroll
  for (int mt = 0; mt < 4; ++mt)
#pragma unroll
    for (int rg = 0; rg < 4; ++rg) {
      int row = mt * 16 + quad * 4 + rg;
      gsum[mt][rg] = sRedB[0][row] + sRedB[1][row] + sRedB[2][row] + sRedB[3][row];
    }

  float* outBase = attn + ((size_t)batch * NQ + q0) * NK;
#pragma unroll
  for (int mt = 0; mt < 4; ++mt)
#pragma unroll
    for (int rg = 0; rg < 4; ++rg) {
      int row = mt * 16 + quad * 4 + rg;
      float inv = 1.0f / gsum[mt][rg];
#pragma unroll
      for (int nt = 0; nt < 8; ++nt)
        outBase[(size_t)row * NK + wn0 + nt * 16 + ln15] = acc[mt][nt][rg] * inv;
    }
  if (w == 0 && ln15 == 0) {
    float tv = Tp[0], bv = Bp[0];
#pragma unroll
    for (int mt = 0; mt < 4; ++mt)
#pragma unroll
      for (int rg = 0; rg < 4; ++rg) {
        int row = mt * 16 + quad * 4 + rg;
        float lse = gmax[mt][rg] + __logf(gsum[mt][rg]);
        float t = (lse + bv) * tv;
        conf[(size_t)batch * NQ + q0 + row] = 1.0f / (1.0f + __expf(-t));
      }
  }
}

extern "C" void kernel_launch(void* const* d_in, const int* in_sizes, int n_in,
                              void* d_out, int out_size, void* d_ws, size_t ws_size,
                              hipStream_t stream) {
  const float* q = (const float*)d_in[0];
  const float* k = (const float*)d_in[1];
  const float* temp = (const float*)d_in[2];
  const float* bias = (const float*)d_in[3];
  float* attn = (float*)d_out;
  float* conf = attn + (size_t)NB * NQ * NK;

  const int nhalfK = NB * NT * 2;   // 2048 K half-tiles

  if (ws_size >= WS_V5) {
    hipLaunchKernelGGL(convert_frag_v7, dim3(2 * nhalfK), dim3(256), 0, stream,
                       q, k, (unsigned char*)d_ws, nhalfK);
    hipLaunchKernelGGL(attn_v5, dim3(256), dim3(512), 0, stream,
                       (const unsigned char*)d_ws, temp, bias, attn, conf);
  } else if (ws_size >= WS_V5K) {
    hipLaunchKernelGGL(convert_frag_v7, dim3(nhalfK), dim3(256), 0, stream,
                       q, k, (unsigned char*)d_ws, nhalfK);
    hipLaunchKernelGGL(attn_v5k, dim3(256), dim3(512), 0, stream,
                       q, (const unsigned char*)d_ws, temp, bias, attn, conf);
  } else {
    hipLaunchKernelGGL(attn_fused_v1, dim3(NB * (NQ / BM1)), dim3(256), 0, stream,
                       q, k, temp, bias, attn, conf);
  }
}